// Round 3
// baseline (80.745 us; speedup 1.0000x reference)
//
#include <hip/hip_runtime.h>
#include <hip/hip_bf16.h>

// 4-qubit QNN, single fused kernel.
// The variational block (shared weights) is a constant 16x16 unitary U;
// <Z_q> = s0^T Re(U^+ Z_q U) s0 with s0 = v(x0) (x) v(x1) (x) v(x0) (x) v(x1),
// v(t) = [cos(t/2), sin(t/2)].  Each output collapses to a 5x5 bilinear form:
//   out_q = sum_{m,n} C[q][m][n] * c0^{4-m} s0^m * c1^{4-n} s1^n
// Every block redundantly builds C (phase 1: one amplitude per LANE, gates as
// __shfl_xor butterflies ~0.4us; phase 1b: LDS reduction to C[100]), then
// streams samples with one thread per (sample, q): 25 coeffs in registers,
// coalesced scalar stores.  One launch total - avoids the setup-kernel
// dependency gap that dominated the controllable time.

__global__ __launch_bounds__(256, 4) void qnn_fused(const float2* __restrict__ x,
                                                    const float* __restrict__ w,
                                                    float* __restrict__ out,
                                                    int B) {
    __shared__ float Ur[16][16];
    __shared__ float Ui[16][16];
    __shared__ float Csh[100];
    const int t = threadIdx.x;

    if (t < 100) Csh[t] = 0.0f;

    // ---- Phase 1: build U.  lane holds amplitude `amp` of column `col`. ----
    {
        const int amp = t & 15;
        const int col = t >> 4;
        float ar = (amp == col) ? 1.0f : 0.0f;
        float ai = 0.0f;

        float wl[36];
#pragma unroll
        for (int i = 0; i < 36; i++) wl[i] = w[i];   // uniform -> scalar loads

#pragma unroll
        for (int l = 0; l < 3; l++) {
#pragma unroll
            for (int wq = 0; wq < 4; wq++) {
                const int st = 1 << (3 - wq);        // wire wq = amplitude bit (3-wq)
                float s, c;
                // RX: a' = c*a - i*s*a_partner  (uniform over lo/hi)
                __sincosf(wl[(l * 4 + wq) * 3 + 0] * 0.5f, &s, &c);
                {
                    const float pr = __shfl_xor(ar, st);
                    const float pi = __shfl_xor(ai, st);
                    const float nr = c * ar + s * pi;
                    const float ni = c * ai - s * pr;
                    ar = nr; ai = ni;
                }
                // RY: a' = c*a + sgn*s*a_partner, sgn = +1 if bit set else -1
                __sincosf(wl[(l * 4 + wq) * 3 + 1] * 0.5f, &s, &c);
                {
                    const float pr = __shfl_xor(ar, st);
                    const float pi = __shfl_xor(ai, st);
                    const float sg = (amp & st) ? s : -s;
                    const float nr = c * ar + sg * pr;
                    const float ni = c * ai + sg * pi;
                    ar = nr; ai = ni;
                }
                // RZ (diagonal): bit clear -> *(c - i s); bit set -> *(c + i s)
                __sincosf(wl[(l * 4 + wq) * 3 + 2] * 0.5f, &s, &c);
                {
                    const float sg = (amp & st) ? -s : s;
                    const float nr = c * ar + sg * ai;
                    const float ni = c * ai - sg * ar;
                    ar = nr; ai = ni;
                }
            }
            // CNOT(ci, (ci+1)%4): if control bit set, take amplitude with
            // target bit flipped.
#pragma unroll
            for (int ci = 0; ci < 4; ci++) {
                const int cst = 1 << (3 - ci);
                const int tst = 1 << (3 - ((ci + 1) & 3));
                const float pr = __shfl_xor(ar, tst);
                const float pi = __shfl_xor(ai, tst);
                if (amp & cst) { ar = pr; ai = pi; }
            }
        }
        Ur[amp][col] = ar;
        Ui[amp][col] = ai;
    }
    __syncthreads();

    // ---- Phase 1b: M_q[i][j] = Re(sum_k conj(U[k][i]) z_q(k) U[k][j]),
    // folded into C[q][m][n]; m = popcount of x0-wire bits (3,1) of (i,j),
    // n = popcount of x1-wire bits (2,0). ----
    {
        const int i = t >> 4;
        const int j = t & 15;
        float m0 = 0.f, m1 = 0.f, m2 = 0.f, m3 = 0.f;
#pragma unroll
        for (int k = 0; k < 16; k++) {
            const float r = Ur[k][i] * Ur[k][j] + Ui[k][i] * Ui[k][j];
            m0 += ((k >> 3) & 1) ? -r : r;
            m1 += ((k >> 2) & 1) ? -r : r;
            m2 += ((k >> 1) & 1) ? -r : r;
            m3 += ((k >> 0) & 1) ? -r : r;
        }
        const int mm = ((i >> 3) & 1) + ((i >> 1) & 1) + ((j >> 3) & 1) + ((j >> 1) & 1);
        const int nn = ((i >> 2) & 1) + (i & 1) + ((j >> 2) & 1) + (j & 1);
        atomicAdd(&Csh[0 * 25 + mm * 5 + nn], m0);
        atomicAdd(&Csh[1 * 25 + mm * 5 + nn], m1);
        atomicAdd(&Csh[2 * 25 + mm * 5 + nn], m2);
        atomicAdd(&Csh[3 * 25 + mm * 5 + nn], m3);
    }
    __syncthreads();

    // ---- Phase 2: stream.  Thread owns output q of samples s_loc + k*stride. ----
    const int q = t & 3;
    float cf[25];
#pragma unroll
    for (int i = 0; i < 25; i++) cf[i] = Csh[q * 25 + i];

    const int s_loc = t >> 2;                 // 0..63
    const int stride = gridDim.x * 64;
    int b = blockIdx.x * 64 + s_loc;
    float2 xv = (b < B) ? x[b] : make_float2(0.f, 0.f);
    while (b < B) {
        const int bn = b + stride;
        float2 xn = make_float2(0.f, 0.f);
        if (bn < B) xn = x[bn];               // prefetch next iteration's x

        float s0, c0, s1, c1;
        __sincosf(xv.x * 0.5f, &s0, &c0);
        __sincosf(xv.y * 0.5f, &s1, &c1);
        const float cc0 = c0 * c0, ss0 = s0 * s0, cs0 = c0 * s0;
        const float cc1 = c1 * c1, ss1 = s1 * s1, cs1 = c1 * s1;
        const float p0[5] = { cc0 * cc0, cc0 * cs0, cs0 * cs0, cs0 * ss0, ss0 * ss0 };
        const float p1[5] = { cc1 * cc1, cc1 * cs1, cs1 * cs1, cs1 * ss1, ss1 * ss1 };
        float acc = 0.0f;
#pragma unroll
        for (int m = 0; m < 5; m++) {
            float inner = 0.0f;
#pragma unroll
            for (int n = 0; n < 5; n++)
                inner = fmaf(cf[m * 5 + n], p1[n], inner);
            acc = fmaf(p0[m], inner, acc);
        }
        out[b * 4 + q] = acc;                 // consecutive threads -> consecutive floats

        b = bn; xv = xn;
    }
}

extern "C" void kernel_launch(void* const* d_in, const int* in_sizes, int n_in,
                              void* d_out, int out_size, void* d_ws, size_t ws_size,
                              hipStream_t stream) {
    const float* x = (const float*)d_in[0];      // (B, 2) float32
    const float* w = (const float*)d_in[1];      // (3, 4, 3) float32
    const int B = in_sizes[0] / 2;

    int grid = (B + 63) / 64;
    if (grid > 1024) grid = 1024;                // 4 blocks/CU; 16 samples/thread at B=1M
    qnn_fused<<<grid, 256, 0, stream>>>((const float2*)x, w, (float*)d_out, B);
}